// Round 3
// baseline (562.065 us; speedup 1.0000x reference)
//
#include <hip/hip_runtime.h>

typedef __attribute__((ext_vector_type(8))) short short8_t;
typedef __attribute__((ext_vector_type(4))) float f32x4_t;

#define DDIM 128
#define BM   32          // rows per tile
#define ROWB 512         // bytes per LDS row (256 bf16)

__device__ __forceinline__ unsigned short f2bf(float x) {
  union { float f; unsigned u; } v; v.f = x;
  unsigned r = v.u + 0x7FFFu + ((v.u >> 16) & 1u);   // RNE
  return (unsigned short)(r >> 16);
}

__device__ __forceinline__ float sigf(float x) {
  return __builtin_amdgcn_rcpf(1.0f + __expf(-x));
}
__device__ __forceinline__ float tanh_fast(float x) {
  return 2.0f * __builtin_amdgcn_rcpf(1.0f + __expf(-2.0f * x)) - 1.0f;
}

// Wt[c][k] = bf16(W[k][c]);  W:[256][640] f32, Wt:[640][256] bf16
__global__ void convert_w_kernel(const float* __restrict__ W,
                                 unsigned short* __restrict__ Wt,
                                 int twoD, int fiveD) {
  const int c = blockIdx.x;
  const int k = threadIdx.x;
  Wt[c * twoD + k] = f2bf(W[k * fiveD + c]);
}

__global__ __launch_bounds__(256)
void treelstm_fused_kernel(const float* __restrict__ h_bot,
                           const float* __restrict__ c_bot,
                           const float* __restrict__ h_buf,
                           const float* __restrict__ c_buf,
                           const int* __restrict__ idx_bl,
                           const int* __restrict__ idx_pl,
                           const int* __restrict__ idx_br,
                           const int* __restrict__ idx_pr,
                           const float* __restrict__ bias,
                           const unsigned short* __restrict__ Wt,
                           float* __restrict__ out,
                           int K, int M, int ntiles) {
  __shared__ __align__(16) char A_lds[BM * ROWB];   // 16 KB, XOR-swizzled bf16 tile

  const int tid = threadIdx.x;

  // staging mapping: 8 threads per row (2 halves x 4 col-segments)
  const int sr    = tid >> 3;          // 0..31 local row
  const int seg   = tid & 7;
  const int shalf = seg >> 2;          // 0: h_l, 1: h_r
  const int scs   = seg & 3;
  char* const sdst = A_lds + sr * ROWB;
  const int sswz  = (sr & 7) << 4;

  // compute mapping: wave w owns d-blocks {w*16, 64+w*16}
  const int w    = tid >> 6;           // 0..3
  const int lane = tid & 63;
  const int l16  = lane & 15;
  const int lq   = lane >> 4;          // 0..3
  const int rswz = (l16 & 7) << 4;

  float* const out_h = out;
  float* const out_c = out + (size_t)M * DDIM;

  int t = blockIdx.x;
  const int stride = gridDim.x;
  if (t >= ntiles) return;

#define LOAD_H(tt, hv)                                                   \
  {                                                                      \
    const int ms = (tt) * BM + sr;                                       \
    int hidx = 0; const float* hsrc;                                     \
    if (shalf == 0) {                                                    \
      if (ms < K) { hidx = idx_bl[ms]; hsrc = h_bot; }                   \
      else        { hidx = (ms < M) ? idx_pl[ms - K] : 0; hsrc = h_buf; }\
    } else {                                                             \
      if (ms < K) { hidx = idx_br[ms]; hsrc = h_bot; }                   \
      else        { hidx = (ms < M) ? idx_pr[ms - K] : 0; hsrc = h_buf; }\
    }                                                                    \
    const float4* s4 = (const float4*)(hsrc + (size_t)hidx * DDIM);      \
    _Pragma("unroll")                                                    \
    for (int q = 0; q < 8; ++q) hv[q] = s4[scs + 4 * q];                 \
  }

#define WRITE_H(hv)                                                      \
  {                                                                      \
    _Pragma("unroll")                                                    \
    for (int q = 0; q < 8; ++q) {                                        \
      const int f4i = scs + 4 * q;                                       \
      ushort4 u;                                                         \
      u.x = f2bf(hv[q].x); u.y = f2bf(hv[q].y);                          \
      u.z = f2bf(hv[q].z); u.w = f2bf(hv[q].w);                          \
      const int byt = (shalf * 256 + f4i * 8) ^ sswz;                    \
      *(ushort4*)(sdst + byt) = u;                                       \
    }                                                                    \
  }

  // ---- prologue: stage tile t ----
  {
    float4 hv[8];
    LOAD_H(t, hv);
    WRITE_H(hv);
  }
  __syncthreads();

  for (;;) {
    const int tn = t + stride;
    const bool more = (tn < ntiles);

    // pipeline: issue next tile's gathered h loads (in flight through GEMM)
    float4 hv2[8];
    if (more) LOAD_H(tn, hv2);

    // current-tile epilogue operands: idx -> c float4 gathers
    const int tb = t * BM;
    int mvec[2];
    f32x4_t cl[2][2], cr[2][2];
    #pragma unroll
    for (int mt = 0; mt < 2; ++mt) {
      const int m = tb + mt * 16 + l16;
      mvec[mt] = m;
      const int mm = (m < M) ? m : 0;
      int il, ir; const float *cls, *crs;
      if (mm < K) { il = idx_bl[mm];     cls = c_bot; }
      else        { il = idx_pl[mm - K]; cls = c_buf; }
      if (mm < K) { ir = idx_br[mm];     crs = c_bot; }
      else        { ir = idx_pr[mm - K]; crs = c_buf; }
      #pragma unroll
      for (int dtb = 0; dtb < 2; ++dtb) {
        const int d0 = dtb * 64 + w * 16 + lq * 4;
        cl[mt][dtb] = *(const f32x4_t*)(cls + (size_t)il * DDIM + d0);
        cr[mt][dtb] = *(const f32x4_t*)(crs + (size_t)ir * DDIM + d0);
      }
    }

    // ---- GEMM on LDS tile t ----
    f32x4_t acc[2][2][5];
    #pragma unroll
    for (int mt = 0; mt < 2; ++mt)
      #pragma unroll
      for (int dtb = 0; dtb < 2; ++dtb)
        #pragma unroll
        for (int g = 0; g < 5; ++g) {
          f32x4_t z = {0.0f, 0.0f, 0.0f, 0.0f};
          acc[mt][dtb][g] = z;
        }

    #pragma unroll
    for (int kk = 0; kk < 8; ++kk) {
      short8_t hf[2];
      #pragma unroll
      for (int mt = 0; mt < 2; ++mt) {
        const int byt = (lq * 16 + kk * 64) ^ rswz;
        hf[mt] = *(const short8_t*)(A_lds + (mt * 16 + l16) * ROWB + byt);
      }
      #pragma unroll
      for (int dtb = 0; dtb < 2; ++dtb)
        #pragma unroll
        for (int g = 0; g < 5; ++g) {
          const int c = g * 128 + dtb * 64 + w * 16 + l16;
          const short8_t wf =
              *(const short8_t*)(Wt + (size_t)c * 256 + lq * 8 + kk * 32);
          #pragma unroll
          for (int mt = 0; mt < 2; ++mt)
            acc[mt][dtb][g] = __builtin_amdgcn_mfma_f32_16x16x32_bf16(
                wf, hf[mt], acc[mt][dtb][g], 0, 0, 0);
        }
    }

    __syncthreads();                 // LDS tile t fully consumed
    if (more) { WRITE_H(hv2); }      // stage t+1; overlaps epilogue below

    // ---- epilogue: gates + LSTM cell + stores ----
    #pragma unroll
    for (int mt = 0; mt < 2; ++mt) {
      if (mvec[mt] < M) {
        #pragma unroll
        for (int dtb = 0; dtb < 2; ++dtb) {
          const int d0 = dtb * 64 + w * 16 + lq * 4;
          f32x4_t bv[5];
          #pragma unroll
          for (int g = 0; g < 5; ++g)
            bv[g] = *(const f32x4_t*)(bias + g * DDIM + d0);
          f32x4_t hv4, cv4;
          #pragma unroll
          for (int j = 0; j < 4; ++j) {
            const float gi = acc[mt][dtb][0][j] + bv[0][j];
            const float go = acc[mt][dtb][1][j] + bv[1][j];
            const float gu = acc[mt][dtb][2][j] + bv[2][j];
            const float gl = acc[mt][dtb][3][j] + bv[3][j];
            const float gr = acc[mt][dtb][4][j] + bv[4][j];
            const float cn = sigf(gi) * tanh_fast(gu)
                           + sigf(gl) * cl[mt][dtb][j]
                           + sigf(gr) * cr[mt][dtb][j];
            const float hn = sigf(go) * tanh_fast(cn);
            cv4[j] = cn; hv4[j] = hn;
          }
          const size_t off = (size_t)mvec[mt] * DDIM + d0;
          *(f32x4_t*)(out_h + off) = hv4;
          *(f32x4_t*)(out_c + off) = cv4;
        }
      }
    }

    if (!more) break;
    __syncthreads();                 // t+1 staged; safe to read next iter
    t = tn;
  }
#undef LOAD_H
#undef WRITE_H
}

extern "C" void kernel_launch(void* const* d_in, const int* in_sizes, int n_in,
                              void* d_out, int out_size, void* d_ws, size_t ws_size,
                              hipStream_t stream) {
  const float* h_bot  = (const float*)d_in[0];
  const float* c_bot  = (const float*)d_in[1];
  const float* h_buf  = (const float*)d_in[2];
  const float* c_buf  = (const float*)d_in[3];
  const int*   idx_bl = (const int*)d_in[4];
  const int*   idx_pl = (const int*)d_in[5];
  const int*   idx_br = (const int*)d_in[6];
  const int*   idx_pr = (const int*)d_in[7];
  const float* W      = (const float*)d_in[8];
  const float* bias   = (const float*)d_in[9];

  const int K = in_sizes[4];
  const int M = 2 * K;
  const int fiveD = in_sizes[9];               // 640
  const int twoD  = in_sizes[8] / fiveD;       // 256

  unsigned short* Wt = (unsigned short*)d_ws;  // [640][256] bf16 = 320 KB

  hipLaunchKernelGGL(convert_w_kernel, dim3(fiveD), dim3(twoD), 0, stream,
                     W, Wt, twoD, fiveD);

  const int ntiles = (M + BM - 1) / BM;
  const int nblocks = 512;                     // 2 blocks/CU, persistent grid-stride
  hipLaunchKernelGGL(treelstm_fused_kernel, dim3(nblocks), dim3(256), 0, stream,
                     h_bot, c_bot, h_buf, c_buf,
                     idx_bl, idx_pl, idx_br, idx_pr,
                     bias, Wt, (float*)d_out, K, M, ntiles);
}